// Round 7
// baseline (288.814 us; speedup 1.0000x reference)
//
#include <hip/hip_runtime.h>
#include <hip/hip_cooperative_groups.h>
#include <cstdint>

namespace cg = cooperative_groups;

// ---------------- problem constants ----------------
#define BATCH 4
#define KCOMP 256
#define GADD 64
#define RADD 64
#define PPK 132            // 4 corners + 64 global + 64 region points per component
#define NPB (KCOMP * PPK)  // 33792 points per batch
#define NTOT (BATCH * NPB) // 135168 points total
#define OUTS 4096
#define INS 4096
#define TBITS 16
#define TSIZE (1 << TBITS) // 65536 hash-table slots per batch
#define TILE 128           // points per tile in the exp phases
#define TILES (NPB / TILE) // 264 tiles per batch
#define MAX_COOP_BLOCKS 1024

#define KEYS_BYTES  ((size_t)BATCH * TSIZE * 8)  // 2 MB   (zeroed in phase 0)
#define DENOM_BYTES ((size_t)BATCH * KCOMP * 4)  // 4 KB   (zeroed in phase 0)
#define VALS_BYTES  ((size_t)BATCH * TSIZE * 4)  // 1 MB   (0xFF in phase 0)
#define PTS_BYTES   ((size_t)NTOT * 4)           // 528 KB (fully written in phase 1)

// phase-0 work partition (uint4-granular; keys+denom contiguous in ws)
#define ZERO_U4 131328     // (KEYS_BYTES + DENOM_BYTES) / 16
#define FF_U4   65536      // VALS_BYTES / 16
#define Y_F4    4096       // BATCH*OUTS/4
#define INIT_TOT (ZERO_U4 + FF_U4 + Y_F4)

__device__ __forceinline__ unsigned long long point_hash(long long t0, long long t1) {
    // (t0+1)^2 * (t1+1)^3, exact in int64 (<= 2^60) — matches ref's unique key.
    // Cross-tuple collisions are SEMANTICS (ref dedups by this key) — do not "fix".
    unsigned long long a = (unsigned long long)((t0 + 1) * (t0 + 1));
    unsigned long long b = (unsigned long long)((t1 + 1) * (t1 + 1) * (t1 + 1));
    return a * b;
}

__device__ __forceinline__ unsigned int slot_of(unsigned long long h) {
    return (unsigned int)((h * 0x9E3779B97F4A7C15ull) >> (64 - TBITS));
}

// ---------- shared device helpers (used by fused and fallback paths) -------
__device__ __forceinline__ void gen_one(int i, const float* __restrict__ means,
                                        const float* __restrict__ rr_u,
                                        const float* __restrict__ g_u,
                                        uint32_t* __restrict__ pts,
                                        unsigned long long* __restrict__ keys,
                                        unsigned int* __restrict__ vals) {
    // Branch-uniform mapping; index math in DOUBLE to match the f64 numpy
    // reference exactly — DO NOT change precision (headroom is 6.25e-4).
    int bk, j;
    long long t0, t1;
    if (i < 4096) {                       // corners: 4 per (b,k)
        bk = i >> 2;
        j = i & 3;                        // FLOOR_MASK: (T,T),(T,F),(F,T),(F,F)
        double m0 = (double)means[bk * 2], m1 = (double)means[bk * 2 + 1];
        t0 = (long long)((j < 2) ? floor(m0) : ceil(m0));
        t1 = (long long)(((j & 1) == 0) ? floor(m1) : ceil(m1));
    } else if (i < 4096 + 65536) {        // global-uniform: 64 per (b,k)
        int i2 = i - 4096;
        bk = i2 >> 6;
        j = 4 + (i2 & 63);
        const float* gp = g_u + (size_t)i2 * 2;      // coalesced
        t0 = (long long)floor((double)gp[0] * (1.0 - 1e-6) * 4096.0);
        t1 = (long long)floor((double)gp[1] * (1.0 - 1e-6) * 4096.0);
    } else {                              // region-uniform: 64 per (b,k)
        int i3 = i - (4096 + 65536);
        bk = i3 >> 6;
        j = 68 + (i3 & 63);
        const float* rp = rr_u + (size_t)i3 * 2;     // coalesced
        double m0 = (double)means[bk * 2], m1 = (double)means[bk * 2 + 1];
        double mr0 = rint(m0), mr1 = rint(m1);
        double lo0 = mr0 - 8.0;
        if (lo0 < 0.0) lo0 = 0.0;
        if (mr0 + 8.0 > 4096.0) lo0 = 4080.0;   // rng - region
        double lo1 = mr1 - 8.0;
        if (lo1 < 0.0) lo1 = 0.0;
        if (mr1 + 8.0 > 4096.0) lo1 = 4080.0;
        t0 = (long long)((double)rp[0] * (1.0 - 1e-6) * 16.0 + lo0); // trunc==floor
        t1 = (long long)((double)rp[1] * (1.0 - 1e-6) * 16.0 + lo1);
    }
    int b = bk >> 8;
    int loc = (bk & 255) * PPK + j;       // reference per-batch point order

    pts[(size_t)b * NPB + loc] = (uint32_t)t0 | ((uint32_t)t1 << 12);

    unsigned long long h = point_hash(t0, t1);
    unsigned long long* kb = keys + (size_t)b * TSIZE;
    unsigned int* vb = vals + (size_t)b * TSIZE;
    unsigned int s = slot_of(h);
    for (;;) {
        unsigned long long prev = atomicCAS(&kb[s], 0ull, h);
        if (prev == 0ull || prev == h) {
            atomicMin(&vb[s], (unsigned int)loc);   // survivor = min index
            break;
        }
        s = (s + 1) & (TSIZE - 1);
    }
}

__device__ __forceinline__ void denom_tile(int b, int tile, int t,
                                           const float* __restrict__ means,
                                           const float* __restrict__ sigmas,
                                           uint32_t* __restrict__ pts,
                                           const unsigned long long* __restrict__ keys,
                                           const unsigned int* __restrict__ vals,
                                           float* __restrict__ denom,
                                           float2* spt) {
    if (t < TILE) {
        int loc = tile * TILE + t;
        uint32_t p = pts[(size_t)b * NPB + loc];
        long long t0 = (long long)(p & 0xFFFu);
        long long t1 = (long long)((p >> 12) & 0xFFFu);
        unsigned long long h = point_hash(t0, t1);
        const unsigned long long* kb = keys + (size_t)b * TSIZE;
        const unsigned int* vb = vals + (size_t)b * TSIZE;
        unsigned int s = slot_of(h);
        while (kb[s] != h) s = (s + 1) & (TSIZE - 1);
        if (vb[s] != (unsigned int)loc) {
            pts[(size_t)b * NPB + loc] = p | 0x80000000u;  // dup flag
            spt[t] = make_float2(1.0e9f, 0.0f);            // sentinel -> exp==0
        } else {
            spt[t] = make_float2((float)t0, (float)t1);
        }
    }
    __syncthreads();

    int bk = b * KCOMP + t;
    float m0 = means[bk * 2], m1 = means[bk * 2 + 1];
    float i0 = -0.5f / (1e-6f + sigmas[bk * 2]);
    float i1 = -0.5f / (1e-6f + sigmas[bk * 2 + 1]);

    float a0 = 0.f, a1 = 0.f, a2 = 0.f, a3 = 0.f, a4 = 0.f, a5 = 0.f, a6 = 0.f, a7 = 0.f;
#pragma unroll 4
    for (int j = 0; j < TILE; j += 8) {
        float2 q0 = spt[j],     q1 = spt[j + 1], q2 = spt[j + 2], q3 = spt[j + 3];
        float2 q4 = spt[j + 4], q5 = spt[j + 5], q6 = spt[j + 6], q7 = spt[j + 7];
        float dx, dy;
        dx = q0.x - m0; dy = q0.y - m1; a0 += __expf(dx * dx * i0 + dy * dy * i1);
        dx = q1.x - m0; dy = q1.y - m1; a1 += __expf(dx * dx * i0 + dy * dy * i1);
        dx = q2.x - m0; dy = q2.y - m1; a2 += __expf(dx * dx * i0 + dy * dy * i1);
        dx = q3.x - m0; dy = q3.y - m1; a3 += __expf(dx * dx * i0 + dy * dy * i1);
        dx = q4.x - m0; dy = q4.y - m1; a4 += __expf(dx * dx * i0 + dy * dy * i1);
        dx = q5.x - m0; dy = q5.y - m1; a5 += __expf(dx * dx * i0 + dy * dy * i1);
        dx = q6.x - m0; dy = q6.y - m1; a6 += __expf(dx * dx * i0 + dy * dy * i1);
        dx = q7.x - m0; dy = q7.y - m1; a7 += __expf(dx * dx * i0 + dy * dy * i1);
    }
    atomicAdd(&denom[bk], ((a0 + a1) + (a2 + a3)) + ((a4 + a5) + (a6 + a7)));
}

__device__ __forceinline__ void scatter_tile(int b, int tile, int t,
                                             const float* __restrict__ means,
                                             const float* __restrict__ sigmas,
                                             const float* __restrict__ values,
                                             const float* __restrict__ denom,
                                             const float* __restrict__ x,
                                             const uint32_t* __restrict__ pts,
                                             float* __restrict__ y,
                                             float4* prm, float* cf, float* wpart) {
    {
        int bk = b * KCOMP + t;
        float i0 = -0.5f / (1e-6f + sigmas[bk * 2]);
        float i1 = -0.5f / (1e-6f + sigmas[bk * 2 + 1]);
        prm[t] = make_float4(means[bk * 2], means[bk * 2 + 1], i0, i1);
        cf[t] = values[bk] / denom[bk];
    }
    __syncthreads();

    int pt_i = t & (TILE - 1);
    int kbase = (t >> 7) * 128;           // 0 or 128
    int loc = tile * TILE + pt_i;
    uint32_t p = pts[(size_t)b * NPB + loc];
    bool live = !(p & 0x80000000u);

    float w = 0.0f;
    if (live) {
        float p0 = (float)(p & 0xFFFu);
        float p1 = (float)((p >> 12) & 0xFFFu);
        float w0 = 0.f, w1 = 0.f, w2 = 0.f, w3 = 0.f, w4 = 0.f, w5 = 0.f, w6 = 0.f, w7 = 0.f;
#pragma unroll 4
        for (int q = kbase; q < kbase + 128; q += 8) {
            float4 r0 = prm[q],     r1 = prm[q + 1], r2 = prm[q + 2], r3 = prm[q + 3];
            float4 r4 = prm[q + 4], r5 = prm[q + 5], r6 = prm[q + 6], r7 = prm[q + 7];
            float dx, dy;
            dx = p0 - r0.x; dy = p1 - r0.y;
            w0 = fmaf(__expf(dx * dx * r0.z + dy * dy * r0.w), cf[q],     w0);
            dx = p0 - r1.x; dy = p1 - r1.y;
            w1 = fmaf(__expf(dx * dx * r1.z + dy * dy * r1.w), cf[q + 1], w1);
            dx = p0 - r2.x; dy = p1 - r2.y;
            w2 = fmaf(__expf(dx * dx * r2.z + dy * dy * r2.w), cf[q + 2], w2);
            dx = p0 - r3.x; dy = p1 - r3.y;
            w3 = fmaf(__expf(dx * dx * r3.z + dy * dy * r3.w), cf[q + 3], w3);
            dx = p0 - r4.x; dy = p1 - r4.y;
            w4 = fmaf(__expf(dx * dx * r4.z + dy * dy * r4.w), cf[q + 4], w4);
            dx = p0 - r5.x; dy = p1 - r5.y;
            w5 = fmaf(__expf(dx * dx * r5.z + dy * dy * r5.w), cf[q + 5], w5);
            dx = p0 - r6.x; dy = p1 - r6.y;
            w6 = fmaf(__expf(dx * dx * r6.z + dy * dy * r6.w), cf[q + 6], w6);
            dx = p0 - r7.x; dy = p1 - r7.y;
            w7 = fmaf(__expf(dx * dx * r7.z + dy * dy * r7.w), cf[q + 7], w7);
        }
        w = ((w0 + w1) + (w2 + w3)) + ((w4 + w5) + (w6 + w7));
    }
    if (t >= TILE) wpart[pt_i] = w;
    __syncthreads();
    if (t < TILE && live) {
        w += wpart[pt_i];
        int out_idx = (int)(p & 0xFFFu);
        int in_idx = (int)((p >> 12) & 0xFFFu);
        atomicAdd(&y[(size_t)b * OUTS + out_idx], w * x[(size_t)b * INS + in_idx]);
    }
}

// ---- fused cooperative kernel: init | gen | dup+denom | scatter -----------
__global__ __launch_bounds__(256, 4)
void k_fused(const float* __restrict__ x, const float* __restrict__ means,
             const float* __restrict__ sigmas, const float* __restrict__ values,
             const float* __restrict__ bias, const float* __restrict__ rr_u,
             const float* __restrict__ g_u, float* __restrict__ y,
             unsigned long long* __restrict__ keys, unsigned int* __restrict__ vals,
             uint32_t* __restrict__ pts, float* __restrict__ denom) {
    cg::grid_group grid = cg::this_grid();
    const int t = threadIdx.x;
    const int nb = gridDim.x;
    const int stride = nb * 256;
    const int gtid0 = blockIdx.x * 256 + t;

    __shared__ float2 spt[TILE];
    __shared__ float4 prm[KCOMP];
    __shared__ float cf[KCOMP];
    __shared__ float wpart[TILE];

    // phase 0: init (keys/denom=0, vals=0xFF, y=bias) — grid-stride
    for (int i = gtid0; i < INIT_TOT; i += stride) {
        if (i < ZERO_U4) {
            ((uint4*)keys)[i] = make_uint4(0u, 0u, 0u, 0u);
        } else if (i < ZERO_U4 + FF_U4) {
            ((uint4*)vals)[i - ZERO_U4] = make_uint4(~0u, ~0u, ~0u, ~0u);
        } else {
            int j = i - (ZERO_U4 + FF_U4);
            ((float4*)y)[j] = ((const float4*)bias)[j & 1023];
        }
    }
    grid.sync();

    // phase 1: generate tuples + hash insert — grid-stride
    for (int i = gtid0; i < NTOT; i += stride)
        gen_one(i, means, rr_u, g_u, pts, keys, vals);
    grid.sync();

    // phase 2: dup-mark + denominator — block-stride over tiles
    for (int tt = blockIdx.x; tt < BATCH * TILES; tt += nb) {
        denom_tile(tt / TILES, tt % TILES, t, means, sigmas, pts, keys, vals,
                   denom, spt);
        __syncthreads();                  // WAR: spt reused next tile
    }
    grid.sync();

    // phase 3: weights + gather + scatter — block-stride over tiles
    for (int tt = blockIdx.x; tt < BATCH * TILES; tt += nb) {
        scatter_tile(tt / TILES, tt % TILES, t, means, sigmas, values, denom,
                     x, pts, y, prm, cf, wpart);
        __syncthreads();                  // WAR: prm/cf/wpart reused next tile
    }
}

// ---------------- fallback kernels (round-5 proven path) -------------------
__global__ void k_init(const float* __restrict__ bias, float* __restrict__ y,
                       uint4* __restrict__ zero_base, uint4* __restrict__ ff_base) {
    int i = blockIdx.x * blockDim.x + threadIdx.x;
    if (i < ZERO_U4) {
        zero_base[i] = make_uint4(0u, 0u, 0u, 0u);
    } else if (i < ZERO_U4 + FF_U4) {
        ff_base[i - ZERO_U4] = make_uint4(~0u, ~0u, ~0u, ~0u);
    } else if (i < INIT_TOT) {
        int j = i - (ZERO_U4 + FF_U4);
        ((float4*)y)[j] = ((const float4*)bias)[j & 1023];
    }
}

__global__ void k_gen(const float* __restrict__ means, const float* __restrict__ rr_u,
                      const float* __restrict__ g_u, uint32_t* __restrict__ pts,
                      unsigned long long* __restrict__ keys,
                      unsigned int* __restrict__ vals) {
    int i = blockIdx.x * blockDim.x + threadIdx.x;
    if (i < NTOT) gen_one(i, means, rr_u, g_u, pts, keys, vals);
}

__global__ void k_denomA(const float* __restrict__ means, const float* __restrict__ sigmas,
                         uint32_t* __restrict__ pts,
                         const unsigned long long* __restrict__ keys,
                         const unsigned int* __restrict__ vals,
                         float* __restrict__ denom) {
    __shared__ float2 spt[TILE];
    denom_tile(blockIdx.x / TILES, blockIdx.x % TILES, threadIdx.x,
               means, sigmas, pts, keys, vals, denom, spt);
}

__global__ void k_scatterB(const float* __restrict__ means, const float* __restrict__ sigmas,
                           const float* __restrict__ values, const float* __restrict__ denom,
                           const float* __restrict__ x, const uint32_t* __restrict__ pts,
                           float* __restrict__ y) {
    __shared__ float4 prm[KCOMP];
    __shared__ float cf[KCOMP];
    __shared__ float wpart[TILE];
    scatter_tile(blockIdx.x / TILES, blockIdx.x % TILES, threadIdx.x,
                 means, sigmas, values, denom, x, pts, y, prm, cf, wpart);
}

// ---------------- launch ----------------
extern "C" void kernel_launch(void* const* d_in, const int* in_sizes, int n_in,
                              void* d_out, int out_size, void* d_ws, size_t ws_size,
                              hipStream_t stream) {
    const float* x      = (const float*)d_in[0];
    const float* means  = (const float*)d_in[1];
    const float* sigmas = (const float*)d_in[2];
    const float* values = (const float*)d_in[3];
    const float* bias   = (const float*)d_in[4];
    const float* rr_u   = (const float*)d_in[5];
    const float* g_u    = (const float*)d_in[6];
    float* y = (float*)d_out;

    // ws layout: [keys 2MB][denom 4KB][vals 1MB][pts 528KB]
    uint8_t* w = (uint8_t*)d_ws;
    unsigned long long* keys = (unsigned long long*)w;
    float* denom = (float*)(w + KEYS_BYTES);
    unsigned int* vals = (unsigned int*)(w + KEYS_BYTES + DENOM_BYTES);
    uint32_t* pts = (uint32_t*)(w + KEYS_BYTES + DENOM_BYTES + VALS_BYTES);

    // Size the cooperative grid from the runtime's own occupancy answer
    // (round-6 lesson: never trust hand arithmetic for coop validation).
    int per_cu = 0;
    hipError_t qerr = hipOccupancyMaxActiveBlocksPerMultiprocessor(
        &per_cu, (const void*)k_fused, 256, 0);
    bool coop_done = false;
    if (qerr == hipSuccess && per_cu >= 1) {
        int grid = per_cu * 256;               // 256 CUs on MI355X
        if (grid > MAX_COOP_BLOCKS) grid = MAX_COOP_BLOCKS;
        void* args[] = { (void*)&x, (void*)&means, (void*)&sigmas, (void*)&values,
                         (void*)&bias, (void*)&rr_u, (void*)&g_u, (void*)&y,
                         (void*)&keys, (void*)&vals, (void*)&pts, (void*)&denom };
        hipError_t lerr = hipLaunchCooperativeKernel((const void*)k_fused,
                                                     dim3(grid), dim3(256),
                                                     args, 0, stream);
        coop_done = (lerr == hipSuccess);
    }
    if (!coop_done) {
        // proven round-5 path (132.1 µs), numerically identical
        hipLaunchKernelGGL(k_init, dim3((INIT_TOT + 255) / 256), dim3(256), 0, stream,
                           bias, y, (uint4*)w, (uint4*)(w + KEYS_BYTES + DENOM_BYTES));
        hipLaunchKernelGGL(k_gen, dim3((NTOT + 255) / 256), dim3(256), 0, stream,
                           means, rr_u, g_u, pts, keys, vals);
        hipLaunchKernelGGL(k_denomA, dim3(BATCH * TILES), dim3(256), 0, stream,
                           means, sigmas, pts, keys, vals, denom);
        hipLaunchKernelGGL(k_scatterB, dim3(BATCH * TILES), dim3(256), 0, stream,
                           means, sigmas, values, denom, x, pts, y);
    }
}

// Round 8
// 129.412 us; speedup vs baseline: 2.2317x; 2.2317x over previous
//
#include <hip/hip_runtime.h>
#include <cstdint>

// ---------------- problem constants ----------------
#define BATCH 4
#define KCOMP 256
#define GADD 64
#define RADD 64
#define PPK 132            // 4 corners + 64 global + 64 region points per component
#define NPB (KCOMP * PPK)  // 33792 points per batch
#define NTOT (BATCH * NPB) // 135168 points total
#define OUTS 4096
#define INS 4096
#define TBITS 16
#define TSIZE (1 << TBITS) // 65536 hash-table slots per batch
#define TILE 128           // points per tile in the exp passes
#define TILES (NPB / TILE) // 264 tiles per batch

#define KEYS_BYTES  ((size_t)BATCH * TSIZE * 8)  // 2 MB   (zeroed by k_init)
#define DENOM_BYTES ((size_t)BATCH * KCOMP * 4)  // 4 KB   (zeroed by k_init)
#define VALS_BYTES  ((size_t)BATCH * TSIZE * 4)  // 1 MB   (0xFF by k_init)
#define PTS_BYTES   ((size_t)NTOT * 4)           // 528 KB (fully written by k_gen)
#define SLOTS_BYTES ((size_t)NTOT * 2)           // 264 KB (fully written by k_gen)

// k_init work partition (uint4-granular; keys+denom contiguous in ws)
#define ZERO_U4 131328     // (KEYS_BYTES + DENOM_BYTES) / 16
#define FF_U4   65536      // VALS_BYTES / 16
#define Y_F4    4096       // BATCH*OUTS/4
#define INIT_TOT (ZERO_U4 + FF_U4 + Y_F4)

__device__ __forceinline__ unsigned long long point_hash(long long t0, long long t1) {
    // (t0+1)^2 * (t1+1)^3, exact in int64 (<= 2^60) — matches ref's unique key.
    // Cross-tuple collisions are SEMANTICS (ref dedups by this key) — do not "fix".
    unsigned long long a = (unsigned long long)((t0 + 1) * (t0 + 1));
    unsigned long long b = (unsigned long long)((t1 + 1) * (t1 + 1) * (t1 + 1));
    return a * b;
}

__device__ __forceinline__ unsigned int slot_of(unsigned long long h) {
    return (unsigned int)((h * 0x9E3779B97F4A7C15ull) >> (64 - TBITS));
}

// ---- kernel 1: fused init — keys/denom=0, vals=0xFF, y=bias ---------------
__global__ void k_init(const float* __restrict__ bias, float* __restrict__ y,
                       uint4* __restrict__ zero_base, uint4* __restrict__ ff_base) {
    int i = blockIdx.x * blockDim.x + threadIdx.x;
    if (i < ZERO_U4) {
        zero_base[i] = make_uint4(0u, 0u, 0u, 0u);
    } else if (i < ZERO_U4 + FF_U4) {
        ff_base[i - ZERO_U4] = make_uint4(~0u, ~0u, ~0u, ~0u);
    } else if (i < INIT_TOT) {
        int j = i - (ZERO_U4 + FF_U4);
        ((float4*)y)[j] = ((const float4*)bias)[j & 1023];
    }
}

// ---- kernel 2: generate integer tuples + hash insert + slot record --------
// Branch-uniform mapping; index math in DOUBLE to match the f64 numpy
// reference exactly — DO NOT change precision (headroom is 6.25e-4).
// Records the point's final table slot so downstream passes skip the probe.
// (Same-key threads provably land on the same slot: keys are write-once and
//  every thread scans the identical linear-probe sequence.)
__global__ void k_gen(const float* __restrict__ means,
                      const float* __restrict__ rr_u,
                      const float* __restrict__ g_u,
                      uint32_t* __restrict__ pts,
                      uint16_t* __restrict__ slots,
                      unsigned long long* __restrict__ keys,
                      unsigned int* __restrict__ vals) {
    int i = blockIdx.x * blockDim.x + threadIdx.x;
    if (i >= NTOT) return;
    int bk, j;
    long long t0, t1;
    if (i < 4096) {                       // corners: 4 per (b,k)
        bk = i >> 2;
        j = i & 3;                        // FLOOR_MASK: (T,T),(T,F),(F,T),(F,F)
        double m0 = (double)means[bk * 2], m1 = (double)means[bk * 2 + 1];
        t0 = (long long)((j < 2) ? floor(m0) : ceil(m0));
        t1 = (long long)(((j & 1) == 0) ? floor(m1) : ceil(m1));
    } else if (i < 4096 + 65536) {        // global-uniform: 64 per (b,k)
        int i2 = i - 4096;
        bk = i2 >> 6;
        j = 4 + (i2 & 63);
        const float* gp = g_u + (size_t)i2 * 2;      // coalesced
        t0 = (long long)floor((double)gp[0] * (1.0 - 1e-6) * 4096.0);
        t1 = (long long)floor((double)gp[1] * (1.0 - 1e-6) * 4096.0);
    } else {                              // region-uniform: 64 per (b,k)
        int i3 = i - (4096 + 65536);
        bk = i3 >> 6;
        j = 68 + (i3 & 63);
        const float* rp = rr_u + (size_t)i3 * 2;     // coalesced
        double m0 = (double)means[bk * 2], m1 = (double)means[bk * 2 + 1];
        double mr0 = rint(m0), mr1 = rint(m1);
        double lo0 = mr0 - 8.0;
        if (lo0 < 0.0) lo0 = 0.0;
        if (mr0 + 8.0 > 4096.0) lo0 = 4080.0;   // rng - region
        double lo1 = mr1 - 8.0;
        if (lo1 < 0.0) lo1 = 0.0;
        if (mr1 + 8.0 > 4096.0) lo1 = 4080.0;
        t0 = (long long)((double)rp[0] * (1.0 - 1e-6) * 16.0 + lo0); // trunc==floor
        t1 = (long long)((double)rp[1] * (1.0 - 1e-6) * 16.0 + lo1);
    }
    int b = bk >> 8;
    int loc = (bk & 255) * PPK + j;       // reference per-batch point order

    pts[(size_t)b * NPB + loc] = (uint32_t)t0 | ((uint32_t)t1 << 12);

    unsigned long long h = point_hash(t0, t1);
    unsigned long long* kb = keys + (size_t)b * TSIZE;
    unsigned int* vb = vals + (size_t)b * TSIZE;
    unsigned int s = slot_of(h);
    for (;;) {
        unsigned long long prev = atomicCAS(&kb[s], 0ull, h);
        if (prev == 0ull || prev == h) {
            atomicMin(&vb[s], (unsigned int)loc);   // survivor = min index
            break;
        }
        s = (s + 1) & (TSIZE - 1);
    }
    slots[(size_t)b * NPB + loc] = (uint16_t)s;
}

// ---- kernel 3: dup-mark + per-(b,k) denominator ---------------------------
// 1056 blocks x 256 thr. Threads t<128 stage one point each (single vals[slot]
// load replaces the hash probe; write dup flag back); every thread owns
// component k=t and loops the 128 LDS points with 8 split accumulators.
__global__ void k_denomA(const float* __restrict__ means,
                         const float* __restrict__ sigmas,
                         uint32_t* __restrict__ pts,
                         const uint16_t* __restrict__ slots,
                         const unsigned int* __restrict__ vals,
                         float* __restrict__ denom) {
    __shared__ float2 spt[TILE];
    int bid = blockIdx.x;
    int b = bid / TILES;
    int tile = bid - b * TILES;
    int t = threadIdx.x;

    if (t < TILE) {
        int loc = tile * TILE + t;
        uint32_t p = pts[(size_t)b * NPB + loc];
        unsigned int s = slots[(size_t)b * NPB + loc];
        if (vals[(size_t)b * TSIZE + s] != (unsigned int)loc) {
            pts[(size_t)b * NPB + loc] = p | 0x80000000u;  // dup: excluded downstream
            spt[t] = make_float2(1.0e9f, 0.0f);            // sentinel -> exp == 0
        } else {
            spt[t] = make_float2((float)(p & 0xFFFu), (float)((p >> 12) & 0xFFFu));
        }
    }
    __syncthreads();

    int bk = b * KCOMP + t;
    float m0 = means[bk * 2], m1 = means[bk * 2 + 1];
    float i0 = -0.5f / (1e-6f + sigmas[bk * 2]);
    float i1 = -0.5f / (1e-6f + sigmas[bk * 2 + 1]);

    float a0 = 0.f, a1 = 0.f, a2 = 0.f, a3 = 0.f, a4 = 0.f, a5 = 0.f, a6 = 0.f, a7 = 0.f;
#pragma unroll 4
    for (int j = 0; j < TILE; j += 8) {
        float2 q0 = spt[j],     q1 = spt[j + 1], q2 = spt[j + 2], q3 = spt[j + 3];
        float2 q4 = spt[j + 4], q5 = spt[j + 5], q6 = spt[j + 6], q7 = spt[j + 7];
        float dx, dy;
        dx = q0.x - m0; dy = q0.y - m1; a0 += __expf(dx * dx * i0 + dy * dy * i1);
        dx = q1.x - m0; dy = q1.y - m1; a1 += __expf(dx * dx * i0 + dy * dy * i1);
        dx = q2.x - m0; dy = q2.y - m1; a2 += __expf(dx * dx * i0 + dy * dy * i1);
        dx = q3.x - m0; dy = q3.y - m1; a3 += __expf(dx * dx * i0 + dy * dy * i1);
        dx = q4.x - m0; dy = q4.y - m1; a4 += __expf(dx * dx * i0 + dy * dy * i1);
        dx = q5.x - m0; dy = q5.y - m1; a5 += __expf(dx * dx * i0 + dy * dy * i1);
        dx = q6.x - m0; dy = q6.y - m1; a6 += __expf(dx * dx * i0 + dy * dy * i1);
        dx = q7.x - m0; dy = q7.y - m1; a7 += __expf(dx * dx * i0 + dy * dy * i1);
    }
    atomicAdd(&denom[bk], ((a0 + a1) + (a2 + a3)) + ((a4 + a5) + (a6 + a7)));
}

// ---- kernel 4: weights + gather + scatter-add -----------------------------
// 1056 blocks x 256 thr; 2 threads per point (k<128 / k>=128), LDS combine.
__global__ void k_scatterB(const float* __restrict__ means,
                           const float* __restrict__ sigmas,
                           const float* __restrict__ values,
                           const float* __restrict__ denom,
                           const float* __restrict__ x,
                           const uint32_t* __restrict__ pts,
                           float* __restrict__ y) {
    __shared__ float4 prm[KCOMP];            // (m0, m1, -0.5*i0, -0.5*i1)
    __shared__ float cf[KCOMP];              // values / denom
    __shared__ float wpart[TILE];
    int bid = blockIdx.x;
    int b = bid / TILES;
    int tile = bid - b * TILES;
    int t = threadIdx.x;

    {
        int bk = b * KCOMP + t;
        float i0 = -0.5f / (1e-6f + sigmas[bk * 2]);
        float i1 = -0.5f / (1e-6f + sigmas[bk * 2 + 1]);
        prm[t] = make_float4(means[bk * 2], means[bk * 2 + 1], i0, i1);
        cf[t] = values[bk] / denom[bk];
    }
    __syncthreads();

    int pt_i = t & (TILE - 1);
    int kbase = (t >> 7) * 128;              // 0 or 128
    int loc = tile * TILE + pt_i;
    uint32_t p = pts[(size_t)b * NPB + loc];
    bool live = !(p & 0x80000000u);

    float w = 0.0f;
    if (live) {
        float p0 = (float)(p & 0xFFFu);
        float p1 = (float)((p >> 12) & 0xFFFu);
        float w0 = 0.f, w1 = 0.f, w2 = 0.f, w3 = 0.f, w4 = 0.f, w5 = 0.f, w6 = 0.f, w7 = 0.f;
#pragma unroll 4
        for (int q = kbase; q < kbase + 128; q += 8) {
            float4 r0 = prm[q],     r1 = prm[q + 1], r2 = prm[q + 2], r3 = prm[q + 3];
            float4 r4 = prm[q + 4], r5 = prm[q + 5], r6 = prm[q + 6], r7 = prm[q + 7];
            float dx, dy;
            dx = p0 - r0.x; dy = p1 - r0.y;
            w0 = fmaf(__expf(dx * dx * r0.z + dy * dy * r0.w), cf[q],     w0);
            dx = p0 - r1.x; dy = p1 - r1.y;
            w1 = fmaf(__expf(dx * dx * r1.z + dy * dy * r1.w), cf[q + 1], w1);
            dx = p0 - r2.x; dy = p1 - r2.y;
            w2 = fmaf(__expf(dx * dx * r2.z + dy * dy * r2.w), cf[q + 2], w2);
            dx = p0 - r3.x; dy = p1 - r3.y;
            w3 = fmaf(__expf(dx * dx * r3.z + dy * dy * r3.w), cf[q + 3], w3);
            dx = p0 - r4.x; dy = p1 - r4.y;
            w4 = fmaf(__expf(dx * dx * r4.z + dy * dy * r4.w), cf[q + 4], w4);
            dx = p0 - r5.x; dy = p1 - r5.y;
            w5 = fmaf(__expf(dx * dx * r5.z + dy * dy * r5.w), cf[q + 5], w5);
            dx = p0 - r6.x; dy = p1 - r6.y;
            w6 = fmaf(__expf(dx * dx * r6.z + dy * dy * r6.w), cf[q + 6], w6);
            dx = p0 - r7.x; dy = p1 - r7.y;
            w7 = fmaf(__expf(dx * dx * r7.z + dy * dy * r7.w), cf[q + 7], w7);
        }
        w = ((w0 + w1) + (w2 + w3)) + ((w4 + w5) + (w6 + w7));
    }
    if (t >= TILE) wpart[pt_i] = w;
    __syncthreads();
    if (t < TILE && live) {
        w += wpart[pt_i];
        int out_idx = (int)(p & 0xFFFu);
        int in_idx = (int)((p >> 12) & 0xFFFu);
        atomicAdd(&y[(size_t)b * OUTS + out_idx], w * x[(size_t)b * INS + in_idx]);
    }
}

// ---------------- launch ----------------
extern "C" void kernel_launch(void* const* d_in, const int* in_sizes, int n_in,
                              void* d_out, int out_size, void* d_ws, size_t ws_size,
                              hipStream_t stream) {
    const float* x      = (const float*)d_in[0];
    const float* means  = (const float*)d_in[1];
    const float* sigmas = (const float*)d_in[2];
    const float* values = (const float*)d_in[3];
    const float* bias   = (const float*)d_in[4];
    const float* rr_u   = (const float*)d_in[5];
    const float* g_u    = (const float*)d_in[6];
    float* y = (float*)d_out;

    // ws layout: [keys 2MB][denom 4KB][vals 1MB][pts 528KB][slots 264KB]
    uint8_t* w = (uint8_t*)d_ws;
    unsigned long long* keys = (unsigned long long*)w;
    float* denom = (float*)(w + KEYS_BYTES);
    unsigned int* vals = (unsigned int*)(w + KEYS_BYTES + DENOM_BYTES);
    uint32_t* pts = (uint32_t*)(w + KEYS_BYTES + DENOM_BYTES + VALS_BYTES);
    uint16_t* slots = (uint16_t*)(w + KEYS_BYTES + DENOM_BYTES + VALS_BYTES + PTS_BYTES);

    hipLaunchKernelGGL(k_init, dim3((INIT_TOT + 255) / 256), dim3(256), 0, stream,
                       bias, y, (uint4*)w, (uint4*)(w + KEYS_BYTES + DENOM_BYTES));
    hipLaunchKernelGGL(k_gen, dim3((NTOT + 255) / 256), dim3(256), 0, stream,
                       means, rr_u, g_u, pts, slots, keys, vals);
    hipLaunchKernelGGL(k_denomA, dim3(BATCH * TILES), dim3(256), 0, stream,
                       means, sigmas, pts, slots, vals, denom);
    hipLaunchKernelGGL(k_scatterB, dim3(BATCH * TILES), dim3(256), 0, stream,
                       means, sigmas, values, denom, x, pts, y);
}